// Round 1
// 223.544 us; speedup vs baseline: 1.1127x; 1.1127x over previous
//
#include <hip/hip_runtime.h>
#include <hip/hip_bf16.h>

#define ALPHA 0.2f
typedef unsigned int uint32;
typedef __attribute__((ext_vector_type(8))) short short8;   // 8 bf16 = 4 VGPRs
typedef __attribute__((ext_vector_type(4))) float f32x4;

static __device__ __forceinline__ unsigned short f2bf(float f) {
    unsigned int u = __float_as_uint(f);
    u += 0x7fffu + ((u >> 16) & 1u);          // RNE
    return (unsigned short)(u >> 16);
}
static __device__ __forceinline__ uint32 pk2bf(float lo, float hi) {
    return (uint32)f2bf(lo) | ((uint32)f2bf(hi) << 16);
}
static __device__ __forceinline__ float bflo(uint32 u) { return __uint_as_float(u << 16); }
static __device__ __forceinline__ float bfhi(uint32 u) { return __uint_as_float(u & 0xffff0000u); }

// ---------------------------------------------------------------------------
// K1 = hist (blocks 0..nbh-1) ∥ prep (blocks nbh..nbh+24).
// hist: counts[dst]++ per edge, record slot-within-node.
// prep: transpose-cast W -> WBT (bf16 [n][c]), Wout -> WoutT (bf16 [n][c]),
//       and s-vector folds w1f = W@a1, w2f = W@a2. (No W@Wout fold anymore:
//       the Wout contraction is deferred to K5 after aggregation.)
// ---------------------------------------------------------------------------
__global__ __launch_bounds__(256) void k1_hist_prep(const int* __restrict__ ei,
                                                    int* __restrict__ counts,
                                                    int* __restrict__ eslot, int E,
                                                    const float* __restrict__ W,
                                                    const float* __restrict__ Wout,
                                                    const float* __restrict__ a1,
                                                    const float* __restrict__ a2,
                                                    unsigned short* __restrict__ WBT,
                                                    unsigned short* __restrict__ WoutT,
                                                    float* __restrict__ w1f,
                                                    float* __restrict__ w2f, int nbh) {
    const int tid = threadIdx.x;
    if ((int)blockIdx.x < nbh) {
        int e = blockIdx.x * 256 + tid;
        if (e < E) eslot[e] = atomicAdd(&counts[ei[E + e]], 1);
        return;
    }
    int bp = blockIdx.x - nbh;
    if (bp < 8) {
        // WBT[n][c] = bf16(W[c][n]) — 16 n-rows per block
        for (int n = bp * 16; n < bp * 16 + 16; ++n)
            for (int c = tid; c < 128; c += 256)
                WBT[n * 128 + c] = f2bf(W[c * 128 + n]);
    } else if (bp < 24) {
        // WoutT[n][c] = bf16(Wout[c][n]), c=0..383 — 8 n-rows per block
        int q = bp - 8;
        for (int n = q * 8; n < q * 8 + 8; ++n)
            for (int c = tid; c < 384; c += 256)
                WoutT[n * 384 + c] = f2bf(Wout[c * 128 + n]);
    } else {
        if (tid < 128) {
            float acc1 = 0.f, acc2 = 0.f;
            for (int c = 0; c < 128; ++c) {
                float w = W[tid * 128 + c];
                acc1 += w * a1[c];
                acc2 += w * a2[c];
            }
            w1f[tid] = acc1;
            w2f[tid] = acc2;
        }
    }
}

// ---------------------------------------------------------------------------
// K2 = mmy (blocks 0..nbm-1) ∥ scan (blocks nbm..).
// mmy: 64-row tiles, single 16x16x32 bf16 MFMA pass Whb = h@W (was 3 passes
//   for Y_k), s1/s2 fused in A-staging. Epilogue: acc -> LDS -> coalesced
//   uint4 stores of bf16 Whb (12.8 MB vs old 38.4 MB Yb).
// scan: rowptr from counts (self-basing re-reduction, L2-resident).
// ---------------------------------------------------------------------------
__global__ __launch_bounds__(256) void k2_mmy_scan(const float* __restrict__ h,
                                                   const unsigned short* __restrict__ WBT,
                                                   const float* __restrict__ w1f,
                                                   const float* __restrict__ w2f,
                                                   unsigned short* __restrict__ Whb,
                                                   float* __restrict__ s1,
                                                   float* __restrict__ s2, int M,
                                                   const int* __restrict__ counts,
                                                   int* __restrict__ rowptr,
                                                   int N, int E, int nbm) {
    __shared__ unsigned short As[64 * 128];   // 16KB
    __shared__ unsigned short Bs[128 * 128];  // 32KB (also epilogue transpose buf)
    __shared__ float ws1[128], ws2[128];
    __shared__ int wsums[4];
    __shared__ int base_s;
    const int tid = threadIdx.x;

    if ((int)blockIdx.x >= nbm) {
        // ---------------- scan ----------------
        const int bs   = blockIdx.x - nbm;
        const int lane = tid & 63, wv = tid >> 6;
        const int limit = bs * 1024;
        int acc = 0;
        for (int i = tid * 4; i < limit; i += 1024) {
            int4 v = *(const int4*)(counts + i);
            acc += v.x + v.y + v.z + v.w;
        }
#pragma unroll
        for (int off = 32; off > 0; off >>= 1) acc += __shfl_down(acc, off);
        if (lane == 0) wsums[wv] = acc;
        __syncthreads();
        if (tid == 0) base_s = wsums[0] + wsums[1] + wsums[2] + wsums[3];
        __syncthreads();
        int i0 = bs * 1024 + tid * 4;
        int v0 = 0, v1 = 0, v2 = 0, v3 = 0;
        if (i0 + 3 < N) {
            int4 v = *(const int4*)(counts + i0);
            v0 = v.x; v1 = v.y; v2 = v.z; v3 = v.w;
        } else {
            if (i0 + 0 < N) v0 = counts[i0 + 0];
            if (i0 + 1 < N) v1 = counts[i0 + 1];
            if (i0 + 2 < N) v2 = counts[i0 + 2];
            if (i0 + 3 < N) v3 = counts[i0 + 3];
        }
        int tt = v0 + v1 + v2 + v3;
        int incl = tt;
#pragma unroll
        for (int off = 1; off < 64; off <<= 1) {
            int t = __shfl_up(incl, off);
            if (lane >= off) incl += t;
        }
        __syncthreads();
        if (lane == 63) wsums[wv] = incl;
        __syncthreads();
        int woff = 0;
        for (int w2 = 0; w2 < wv; ++w2) woff += wsums[w2];
        int base = base_s + woff + (incl - tt);
        if (i0 + 0 < N) rowptr[i0 + 0] = base;
        if (i0 + 1 < N) rowptr[i0 + 1] = base + v0;
        if (i0 + 2 < N) rowptr[i0 + 2] = base + v0 + v1;
        if (i0 + 3 < N) rowptr[i0 + 3] = base + v0 + v1 + v2;
        if (bs == 0 && tid == 0) rowptr[N] = E;
        return;
    }

    // ---------------- mmy (64-row tile) ----------------
    const int lane = tid & 63;
    const int w    = tid >> 6;
    const int row0 = blockIdx.x * 64;

    if (tid < 128) ws1[tid] = w1f[tid];
    else           ws2[tid - 128] = w2f[tid - 128];
    __syncthreads();

    // stage A (fp32 -> bf16) + fused fp32 score partials
    const float4* h4 = (const float4*)h;
    float sp1[4], sp2[4];
#pragma unroll
    for (int m = 0; m < 4; ++m) { sp1[m] = 0.f; sp2[m] = 0.f; }
#pragma unroll
    for (int m = 0; m < 4; ++m) {
        int i = m * 256 + tid;            // 0..1023
        int r = i >> 4, g = i & 15;
        int rg = row0 + r;
        float4 va = make_float4(0.f, 0.f, 0.f, 0.f), vb = va;
        if (rg < M) {
            va = h4[(size_t)rg * 32 + g * 2];
            vb = h4[(size_t)rg * 32 + g * 2 + 1];
        }
        float4 wa1 = *(const float4*)(ws1 + g * 8);
        float4 wb1 = *(const float4*)(ws1 + g * 8 + 4);
        float4 wa2 = *(const float4*)(ws2 + g * 8);
        float4 wb2 = *(const float4*)(ws2 + g * 8 + 4);
        sp1[m] += va.x * wa1.x + va.y * wa1.y + va.z * wa1.z + va.w * wa1.w
                + vb.x * wb1.x + vb.y * wb1.y + vb.z * wb1.z + vb.w * wb1.w;
        sp2[m] += va.x * wa2.x + va.y * wa2.y + va.z * wa2.z + va.w * wa2.w
                + vb.x * wb2.x + vb.y * wb2.y + vb.z * wb2.z + vb.w * wb2.w;
        uint4 u;
        u.x = pk2bf(va.x, va.y); u.y = pk2bf(va.z, va.w);
        u.z = pk2bf(vb.x, vb.y); u.w = pk2bf(vb.z, vb.w);
        *(uint4*)(As + r * 128 + ((g ^ (r & 15)) * 8)) = u;
    }
#pragma unroll
    for (int m = 0; m < 4; ++m) {
#pragma unroll
        for (int off = 1; off < 16; off <<= 1) {
            sp1[m] += __shfl_xor(sp1[m], off);
            sp2[m] += __shfl_xor(sp2[m], off);
        }
    }
    if ((tid & 15) == 0) {
#pragma unroll
        for (int m = 0; m < 4; ++m) {
            int rg = row0 + m * 16 + (tid >> 4);
            if (rg < M) { s1[rg] = sp1[m]; s2[rg] = sp2[m]; }
        }
    }

    // stage B = WBT (128 n-rows, 128 k)
#pragma unroll
    for (int m = 0; m < 8; ++m) {
        int i = m * 256 + tid;
        int n = i >> 4, g = i & 15;
        uint4 v = *(const uint4*)(WBT + n * 128 + g * 8);
        *(uint4*)(Bs + n * 128 + ((g ^ (n & 15)) * 8)) = v;
    }
    __syncthreads();

    const int ml   = lane & 15;
    const int quad = lane >> 4;
    f32x4 acc[8];
#pragma unroll
    for (int nt = 0; nt < 8; ++nt) acc[nt] = (f32x4){0.f, 0.f, 0.f, 0.f};
#pragma unroll
    for (int kc = 0; kc < 4; ++kc) {
        int gl = ((kc * 4 + quad) ^ ml) * 8;
        short8 af = *(const short8*)(As + (w * 16 + ml) * 128 + gl);
#pragma unroll
        for (int nt = 0; nt < 8; ++nt) {
            short8 bf = *(const short8*)(Bs + (nt * 16 + ml) * 128 + gl);
            acc[nt] = __builtin_amdgcn_mfma_f32_16x16x32_bf16(af, bf, acc[nt], 0, 0, 0);
        }
    }
    // epilogue: acc -> Ct (=Bs, free now) -> coalesced uint4 stores of Whb
    __syncthreads();                  // all waves done reading As/Bs
    unsigned short* Ct = Bs;          // stride 136 shorts (272B, 16B-aligned)
    int lrow = w * 16 + quad * 4;
#pragma unroll
    for (int r = 0; r < 4; ++r)
#pragma unroll
        for (int nt = 0; nt < 8; ++nt)
            Ct[(lrow + r) * 136 + nt * 16 + ml] = f2bf(acc[nt][r]);
    __syncthreads();
#pragma unroll
    for (int m = 0; m < 4; ++m) {
        int i = m * 256 + tid;        // 0..1023
        int r2 = i >> 4, g = i & 15;
        int rg = row0 + r2;
        uint4 v = *(const uint4*)(Ct + r2 * 136 + g * 8);
        if (rg < M)
            *(uint4*)(Whb + (size_t)rg * 128 + g * 8) = v;
    }
}

// ---------------------------------------------------------------------------
// scatter: pos = rowptr[dst] + eslot[e]; write 8B record
// {src:17b | ex0:15b, ex1:15b | ex2:15b<<15} — ex>0 always so the bf16 sign
// bit is free; halves the random-write traffic vs 16B records.
// Max-shift skipped: softmax shift-invariant, scores bounded, eps negligible.
// ---------------------------------------------------------------------------
__global__ __launch_bounds__(256) void scatter_kernel(const int* __restrict__ ei,
                                                      const float* __restrict__ ef,
                                                      const float* __restrict__ s1,
                                                      const float* __restrict__ s2,
                                                      const int* __restrict__ rowptr,
                                                      const int* __restrict__ eslot,
                                                      uint2* __restrict__ rec8, int E) {
    int e = blockIdx.x * blockDim.x + threadIdx.x;
    if (e >= E) return;
    int src = ei[e];
    int dst = ei[E + e];
    float s = s1[src] + s2[dst];
    s = (s >= 0.f) ? s : ALPHA * s;
    unsigned short b0 = f2bf(__expf(s * ef[e * 3 + 0]));
    unsigned short b1 = f2bf(__expf(s * ef[e * 3 + 1]));
    unsigned short b2 = f2bf(__expf(s * ef[e * 3 + 2]));
    uint2 rv;
    rv.x = (uint32)src | ((uint32)(b0 & 0x7fffu) << 17);
    rv.y = (uint32)(b1 & 0x7fffu) | ((uint32)(b2 & 0x7fffu) << 15);
    int pos = rowptr[dst] + eslot[e];
    rec8[pos] = rv;
}

// ---------------------------------------------------------------------------
// agg: one wave per node, atomic-free, ONE pass. Gathers Whb[src] (256B/edge,
// 3x less than old Y gather) and accumulates unnormalized z_k plus the
// denominators d_k redundantly per-lane (broadcast rec8 load -> no shuffles,
// no denom pre-pass). Normalizes once at the end; emits z as bf16 rows
// [k0 c0..127 | k1 ... | k2 ...] ready for the K5 GEMM A-operand.
// ---------------------------------------------------------------------------
__global__ __launch_bounds__(256) void agg_kernel(const uint2* __restrict__ rec8,
                                                  const int* __restrict__ rowptr,
                                                  const uint32* __restrict__ Yu,
                                                  uint32* __restrict__ zo, int N) {
    int node = (blockIdx.x * blockDim.x + threadIdx.x) >> 6;
    int lane = threadIdx.x & 63;
    if (node >= N) return;
    int beg = rowptr[node], end = rowptr[node + 1];

    float d0 = 0.f, d1 = 0.f, d2 = 0.f;
    float z0l = 0.f, z0h = 0.f, z1l = 0.f, z1h = 0.f, z2l = 0.f, z2h = 0.f;
    int j = beg;
    for (; j + 3 < end; j += 4) {
        uint2 r0 = rec8[j], r1 = rec8[j + 1], r2 = rec8[j + 2], r3 = rec8[j + 3];
        uint32 u0 = Yu[(size_t)(r0.x & 0x1ffffu) * 64 + lane];
        uint32 u1 = Yu[(size_t)(r1.x & 0x1ffffu) * 64 + lane];
        uint32 u2 = Yu[(size_t)(r2.x & 0x1ffffu) * 64 + lane];
        uint32 u3 = Yu[(size_t)(r3.x & 0x1ffffu) * 64 + lane];
        float w00 = __uint_as_float((r0.x >> 1) & 0x7fff0000u);
        float w01 = __uint_as_float((r0.y << 16) & 0x7fff0000u);
        float w02 = __uint_as_float((r0.y << 1) & 0x7fff0000u);
        float w10 = __uint_as_float((r1.x >> 1) & 0x7fff0000u);
        float w11 = __uint_as_float((r1.y << 16) & 0x7fff0000u);
        float w12 = __uint_as_float((r1.y << 1) & 0x7fff0000u);
        float w20 = __uint_as_float((r2.x >> 1) & 0x7fff0000u);
        float w21 = __uint_as_float((r2.y << 16) & 0x7fff0000u);
        float w22 = __uint_as_float((r2.y << 1) & 0x7fff0000u);
        float w30 = __uint_as_float((r3.x >> 1) & 0x7fff0000u);
        float w31 = __uint_as_float((r3.y << 16) & 0x7fff0000u);
        float w32 = __uint_as_float((r3.y << 1) & 0x7fff0000u);
        d0 += w00 + w10 + w20 + w30;
        d1 += w01 + w11 + w21 + w31;
        d2 += w02 + w12 + w22 + w32;
        float y0l = bflo(u0), y0h = bfhi(u0);
        float y1l = bflo(u1), y1h = bfhi(u1);
        float y2l = bflo(u2), y2h = bfhi(u2);
        float y3l = bflo(u3), y3h = bfhi(u3);
        z0l += w00 * y0l + w10 * y1l + w20 * y2l + w30 * y3l;
        z0h += w00 * y0h + w10 * y1h + w20 * y2h + w30 * y3h;
        z1l += w01 * y0l + w11 * y1l + w21 * y2l + w31 * y3l;
        z1h += w01 * y0h + w11 * y1h + w21 * y2h + w31 * y3h;
        z2l += w02 * y0l + w12 * y1l + w22 * y2l + w32 * y3l;
        z2h += w02 * y0h + w12 * y1h + w22 * y2h + w32 * y3h;
    }
    for (; j < end; ++j) {
        uint2 r0 = rec8[j];
        uint32 u0 = Yu[(size_t)(r0.x & 0x1ffffu) * 64 + lane];
        float w00 = __uint_as_float((r0.x >> 1) & 0x7fff0000u);
        float w01 = __uint_as_float((r0.y << 16) & 0x7fff0000u);
        float w02 = __uint_as_float((r0.y << 1) & 0x7fff0000u);
        d0 += w00; d1 += w01; d2 += w02;
        float y0l = bflo(u0), y0h = bfhi(u0);
        z0l += w00 * y0l; z0h += w00 * y0h;
        z1l += w01 * y0l; z1h += w01 * y0h;
        z2l += w02 * y0l; z2h += w02 * y0h;
    }
    float i0 = 1.f / (d0 + 1e-16f);
    float i1 = 1.f / (d1 + 1e-16f);
    float i2 = 1.f / (d2 + 1e-16f);
    size_t zb = (size_t)node * 192;
    zo[zb + lane]       = pk2bf(z0l * i0, z0h * i0);
    zo[zb + 64 + lane]  = pk2bf(z1l * i1, z1h * i1);
    zo[zb + 128 + lane] = pk2bf(z2l * i2, z2h * i2);
}

// ---------------------------------------------------------------------------
// K5: out[N,128] = z[N,384] @ Wout[384,128]. 64-row tiles, 3 k-slices of 128
// staged in LDS (same MFMA microkernel as mmy). Epilogue: fp32 acc -> LDS
// transpose (stride 132 floats) -> coalesced float4 stores.
// ---------------------------------------------------------------------------
__global__ __launch_bounds__(256) void k5_gemm(const unsigned short* __restrict__ z,
                                               const unsigned short* __restrict__ WoutT,
                                               float* __restrict__ out, int M) {
    __shared__ __align__(16) char smem[49152];
    unsigned short* As = (unsigned short*)smem;            // 64*128 bf16 = 16KB
    unsigned short* Bs = (unsigned short*)(smem + 16384);  // 128*128 bf16 = 32KB
    float* Ct = (float*)smem;                              // 64*132 f32 = 33.8KB (epilogue)
    const int tid = threadIdx.x;
    const int lane = tid & 63, w = tid >> 6;
    const int ml = lane & 15, quad = lane >> 4;
    const int row0 = blockIdx.x * 64;

    f32x4 acc[8];
#pragma unroll
    for (int nt = 0; nt < 8; ++nt) acc[nt] = (f32x4){0.f, 0.f, 0.f, 0.f};

    for (int ks = 0; ks < 3; ++ks) {
        __syncthreads();              // prev slice compute done
#pragma unroll
        for (int m = 0; m < 4; ++m) { // stage A slice: 64 rows x 128 bf16
            int i = m * 256 + tid;
            int r = i >> 4, g = i & 15;
            int rg = row0 + r;
            uint4 v = make_uint4(0u, 0u, 0u, 0u);
            if (rg < M) v = *(const uint4*)(z + (size_t)rg * 384 + ks * 128 + g * 8);
            *(uint4*)(As + r * 128 + ((g ^ (r & 15)) * 8)) = v;
        }
#pragma unroll
        for (int m = 0; m < 8; ++m) { // stage B slice: 128 n-rows x 128 k
            int i = m * 256 + tid;
            int n = i >> 4, g = i & 15;
            uint4 v = *(const uint4*)(WoutT + n * 384 + ks * 128 + g * 8);
            *(uint4*)(Bs + n * 128 + ((g ^ (n & 15)) * 8)) = v;
        }
        __syncthreads();
#pragma unroll
        for (int kc = 0; kc < 4; ++kc) {
            int gl = ((kc * 4 + quad) ^ ml) * 8;
            short8 af = *(const short8*)(As + (w * 16 + ml) * 128 + gl);
#pragma unroll
            for (int nt = 0; nt < 8; ++nt) {
                short8 bf = *(const short8*)(Bs + (nt * 16 + ml) * 128 + gl);
                acc[nt] = __builtin_amdgcn_mfma_f32_16x16x32_bf16(af, bf, acc[nt], 0, 0, 0);
            }
        }
    }
    __syncthreads();
    int lrow = w * 16 + quad * 4;
#pragma unroll
    for (int r = 0; r < 4; ++r)
#pragma unroll
        for (int nt = 0; nt < 8; ++nt)
            Ct[(lrow + r) * 132 + nt * 16 + ml] = acc[nt][r];
    __syncthreads();
#pragma unroll
    for (int m = 0; m < 8; ++m) {
        int i = m * 256 + tid;
        int r2 = i >> 5, g = i & 31;
        int rg = row0 + r2;
        if (rg < M)
            *(float4*)(out + (size_t)rg * 128 + g * 4) = *(const float4*)(Ct + r2 * 132 + g * 4);
    }
}

// ---------------------------------------------------------------------------
extern "C" void kernel_launch(void* const* d_in, const int* in_sizes, int n_in,
                              void* d_out, int out_size, void* d_ws, size_t ws_size,
                              hipStream_t stream) {
    const float* h    = (const float*)d_in[0];
    const int*   ei   = (const int*)d_in[1];    // [2, E]
    const float* ef   = (const float*)d_in[2];  // [E, 3]
    const float* W    = (const float*)d_in[3];  // [128,128]
    const float* a1   = (const float*)d_in[4];  // [128]
    const float* a2   = (const float*)d_in[5];  // [128]
    const float* Wout = (const float*)d_in[6];  // [384,128]
    float*       out  = (float*)d_out;

    const int N = in_sizes[0] / 128;  // 50000
    const int E = in_sizes[2] / 3;    // 800000
    const int nchunk = (N + 1023) / 1024;
    const int nbh    = (E + 255) / 256;   // hist blocks
    const int nbm    = (N + 63) / 64;     // mmy blocks

    // workspace layout (rec8 first -> 16B alignment for everything vectorized)
    uint2* rec8 = (uint2*)d_ws;                           // E * 8B
    unsigned short* Whb = (unsigned short*)(rec8 + E);    // N*128 bf16 (12.8MB)
    unsigned short* WBT = Whb + (size_t)N * 128;          // 128*128 bf16
    unsigned short* WoutT = WBT + 128 * 128;              // 128*384 bf16
    float* w1f  = (float*)(WoutT + 128 * 384);            // 128
    float* w2f  = w1f + 128;                              // 128
    float* s1   = w2f + 128;                              // N
    float* s2   = s1 + N;                                 // N
    int* rowptr = (int*)(s2 + N);                         // N+1 (padded to N+4 for 16B align)
    unsigned short* zbuf = (unsigned short*)(rowptr + N + 4);  // N*384 bf16 (38.4MB)
    // counts/eslot alias zbuf: dead before agg writes z (sequential stream order)
    int* counts = (int*)zbuf;                             // N
    int* eslot  = counts + N;                             // E

    (void)hipMemsetAsync(counts, 0, (size_t)N * sizeof(int), stream);

    k1_hist_prep<<<nbh + 25, 256, 0, stream>>>(ei, counts, eslot, E,
                                               W, Wout, a1, a2, WBT, WoutT, w1f, w2f, nbh);
    k2_mmy_scan<<<nbm + nchunk, 256, 0, stream>>>(h, WBT, w1f, w2f, Whb, s1, s2, N,
                                                  counts, rowptr, N, E, nbm);
    scatter_kernel<<<(E + 255) / 256, 256, 0, stream>>>(ei, ef, s1, s2, rowptr, eslot, rec8, E);
    agg_kernel<<<(N * 64 + 255) / 256, 256, 0, stream>>>(rec8, rowptr, (const uint32*)Whb,
                                                         (uint32*)zbuf, N);
    k5_gemm<<<(N + 63) / 64, 256, 0, stream>>>(zbuf, WoutT, out, N);
}

// Round 2
// 217.219 us; speedup vs baseline: 1.1451x; 1.0291x over previous
//
#include <hip/hip_runtime.h>
#include <hip/hip_bf16.h>

#define ALPHA 0.2f
typedef unsigned int uint32;
typedef __attribute__((ext_vector_type(8))) short short8;   // 8 bf16 = 4 VGPRs
typedef __attribute__((ext_vector_type(4))) float f32x4;

static __device__ __forceinline__ unsigned short f2bf(float f) {
    unsigned int u = __float_as_uint(f);
    u += 0x7fffu + ((u >> 16) & 1u);          // RNE
    return (unsigned short)(u >> 16);
}
static __device__ __forceinline__ uint32 pk2bf(float lo, float hi) {
    return (uint32)f2bf(lo) | ((uint32)f2bf(hi) << 16);
}
static __device__ __forceinline__ float bflo(uint32 u) { return __uint_as_float(u << 16); }
static __device__ __forceinline__ float bfhi(uint32 u) { return __uint_as_float(u & 0xffff0000u); }

// ---------------------------------------------------------------------------
// K1 = hist (blocks 0..nbh-1) ∥ prep (blocks nbh..nbh+24).
// hist: counts[dst]++ per edge, record slot-within-node.
// prep: transpose-cast W -> WBT (bf16 [n][c]), Wout -> WoutT (bf16 [n][c]),
//       and s-vector folds w1f = W@a1, w2f = W@a2.
// ---------------------------------------------------------------------------
__global__ __launch_bounds__(256) void k1_hist_prep(const int* __restrict__ ei,
                                                    int* __restrict__ counts,
                                                    int* __restrict__ eslot, int E,
                                                    const float* __restrict__ W,
                                                    const float* __restrict__ Wout,
                                                    const float* __restrict__ a1,
                                                    const float* __restrict__ a2,
                                                    unsigned short* __restrict__ WBT,
                                                    unsigned short* __restrict__ WoutT,
                                                    float* __restrict__ w1f,
                                                    float* __restrict__ w2f, int nbh) {
    const int tid = threadIdx.x;
    if ((int)blockIdx.x < nbh) {
        int e = blockIdx.x * 256 + tid;
        if (e < E) eslot[e] = atomicAdd(&counts[ei[E + e]], 1);
        return;
    }
    int bp = blockIdx.x - nbh;
    if (bp < 8) {
        // WBT[n][c] = bf16(W[c][n]) — 16 n-rows per block
        for (int n = bp * 16; n < bp * 16 + 16; ++n)
            for (int c = tid; c < 128; c += 256)
                WBT[n * 128 + c] = f2bf(W[c * 128 + n]);
    } else if (bp < 24) {
        // WoutT[n][c] = bf16(Wout[c][n]), c=0..383 — 8 n-rows per block
        int q = bp - 8;
        for (int n = q * 8; n < q * 8 + 8; ++n)
            for (int c = tid; c < 384; c += 256)
                WoutT[n * 384 + c] = f2bf(Wout[c * 128 + n]);
    } else {
        if (tid < 128) {
            float acc1 = 0.f, acc2 = 0.f;
            for (int c = 0; c < 128; ++c) {
                float w = W[tid * 128 + c];
                acc1 += w * a1[c];
                acc2 += w * a2[c];
            }
            w1f[tid] = acc1;
            w2f[tid] = acc2;
        }
    }
}

// ---------------------------------------------------------------------------
// K2 = mmy (blocks 0..nbm-1) ∥ scan (blocks nbm..).
// mmy: 64-row tiles, 16x16x32 bf16 MFMA, Whb = h@W, s1/s2 fused in A-staging.
//   s2 goes into PR[n].x (interleaved with scan's rowptr in PR[n].y) so
//   scatter does ONE random 8B gather per dst instead of two 4B gathers.
// scan: rowptr from counts (self-basing re-reduction, L2-resident).
// ---------------------------------------------------------------------------
__global__ __launch_bounds__(256) void k2_mmy_scan(const float* __restrict__ h,
                                                   const unsigned short* __restrict__ WBT,
                                                   const float* __restrict__ w1f,
                                                   const float* __restrict__ w2f,
                                                   unsigned short* __restrict__ Whb,
                                                   float* __restrict__ s1,
                                                   uint2* __restrict__ PR, int M,
                                                   const int* __restrict__ counts,
                                                   int* __restrict__ rowptr,
                                                   int N, int E, int nbm) {
    __shared__ unsigned short As[64 * 128];   // 16KB
    __shared__ unsigned short Bs[128 * 128];  // 32KB (also epilogue transpose buf)
    __shared__ float ws1[128], ws2[128];
    __shared__ int wsums[4];
    __shared__ int base_s;
    const int tid = threadIdx.x;

    if ((int)blockIdx.x >= nbm) {
        // ---------------- scan ----------------
        const int bs   = blockIdx.x - nbm;
        const int lane = tid & 63, wv = tid >> 6;
        const int limit = bs * 1024;
        int acc = 0;
        for (int i = tid * 4; i < limit; i += 1024) {
            int4 v = *(const int4*)(counts + i);
            acc += v.x + v.y + v.z + v.w;
        }
#pragma unroll
        for (int off = 32; off > 0; off >>= 1) acc += __shfl_down(acc, off);
        if (lane == 0) wsums[wv] = acc;
        __syncthreads();
        if (tid == 0) base_s = wsums[0] + wsums[1] + wsums[2] + wsums[3];
        __syncthreads();
        int i0 = bs * 1024 + tid * 4;
        int v0 = 0, v1 = 0, v2 = 0, v3 = 0;
        if (i0 + 3 < N) {
            int4 v = *(const int4*)(counts + i0);
            v0 = v.x; v1 = v.y; v2 = v.z; v3 = v.w;
        } else {
            if (i0 + 0 < N) v0 = counts[i0 + 0];
            if (i0 + 1 < N) v1 = counts[i0 + 1];
            if (i0 + 2 < N) v2 = counts[i0 + 2];
            if (i0 + 3 < N) v3 = counts[i0 + 3];
        }
        int tt = v0 + v1 + v2 + v3;
        int incl = tt;
#pragma unroll
        for (int off = 1; off < 64; off <<= 1) {
            int t = __shfl_up(incl, off);
            if (lane >= off) incl += t;
        }
        __syncthreads();
        if (lane == 63) wsums[wv] = incl;
        __syncthreads();
        int woff = 0;
        for (int w2 = 0; w2 < wv; ++w2) woff += wsums[w2];
        int base = base_s + woff + (incl - tt);
        if (i0 + 0 < N) { rowptr[i0 + 0] = base;                PR[i0 + 0].y = (uint32)base; }
        if (i0 + 1 < N) { rowptr[i0 + 1] = base + v0;           PR[i0 + 1].y = (uint32)(base + v0); }
        if (i0 + 2 < N) { rowptr[i0 + 2] = base + v0 + v1;      PR[i0 + 2].y = (uint32)(base + v0 + v1); }
        if (i0 + 3 < N) { rowptr[i0 + 3] = base + v0 + v1 + v2; PR[i0 + 3].y = (uint32)(base + v0 + v1 + v2); }
        if (bs == 0 && tid == 0) rowptr[N] = E;
        return;
    }

    // ---------------- mmy (64-row tile) ----------------
    const int lane = tid & 63;
    const int w    = tid >> 6;
    const int row0 = blockIdx.x * 64;

    if (tid < 128) ws1[tid] = w1f[tid];
    else           ws2[tid - 128] = w2f[tid - 128];
    __syncthreads();

    // stage A (fp32 -> bf16) + fused fp32 score partials
    const float4* h4 = (const float4*)h;
    float sp1[4], sp2[4];
#pragma unroll
    for (int m = 0; m < 4; ++m) { sp1[m] = 0.f; sp2[m] = 0.f; }
#pragma unroll
    for (int m = 0; m < 4; ++m) {
        int i = m * 256 + tid;            // 0..1023
        int r = i >> 4, g = i & 15;
        int rg = row0 + r;
        float4 va = make_float4(0.f, 0.f, 0.f, 0.f), vb = va;
        if (rg < M) {
            va = h4[(size_t)rg * 32 + g * 2];
            vb = h4[(size_t)rg * 32 + g * 2 + 1];
        }
        float4 wa1 = *(const float4*)(ws1 + g * 8);
        float4 wb1 = *(const float4*)(ws1 + g * 8 + 4);
        float4 wa2 = *(const float4*)(ws2 + g * 8);
        float4 wb2 = *(const float4*)(ws2 + g * 8 + 4);
        sp1[m] += va.x * wa1.x + va.y * wa1.y + va.z * wa1.z + va.w * wa1.w
                + vb.x * wb1.x + vb.y * wb1.y + vb.z * wb1.z + vb.w * wb1.w;
        sp2[m] += va.x * wa2.x + va.y * wa2.y + va.z * wa2.z + va.w * wa2.w
                + vb.x * wb2.x + vb.y * wb2.y + vb.z * wb2.z + vb.w * wb2.w;
        uint4 u;
        u.x = pk2bf(va.x, va.y); u.y = pk2bf(va.z, va.w);
        u.z = pk2bf(vb.x, vb.y); u.w = pk2bf(vb.z, vb.w);
        *(uint4*)(As + r * 128 + ((g ^ (r & 15)) * 8)) = u;
    }
#pragma unroll
    for (int m = 0; m < 4; ++m) {
#pragma unroll
        for (int off = 1; off < 16; off <<= 1) {
            sp1[m] += __shfl_xor(sp1[m], off);
            sp2[m] += __shfl_xor(sp2[m], off);
        }
    }
    if ((tid & 15) == 0) {
#pragma unroll
        for (int m = 0; m < 4; ++m) {
            int rg = row0 + m * 16 + (tid >> 4);
            if (rg < M) { s1[rg] = sp1[m]; PR[rg].x = __float_as_uint(sp2[m]); }
        }
    }

    // stage B = WBT (128 n-rows, 128 k)
#pragma unroll
    for (int m = 0; m < 8; ++m) {
        int i = m * 256 + tid;
        int n = i >> 4, g = i & 15;
        uint4 v = *(const uint4*)(WBT + n * 128 + g * 8);
        *(uint4*)(Bs + n * 128 + ((g ^ (n & 15)) * 8)) = v;
    }
    __syncthreads();

    const int ml   = lane & 15;
    const int quad = lane >> 4;
    f32x4 acc[8];
#pragma unroll
    for (int nt = 0; nt < 8; ++nt) acc[nt] = (f32x4){0.f, 0.f, 0.f, 0.f};
#pragma unroll
    for (int kc = 0; kc < 4; ++kc) {
        int gl = ((kc * 4 + quad) ^ ml) * 8;
        short8 af = *(const short8*)(As + (w * 16 + ml) * 128 + gl);
#pragma unroll
        for (int nt = 0; nt < 8; ++nt) {
            short8 bf = *(const short8*)(Bs + (nt * 16 + ml) * 128 + gl);
            acc[nt] = __builtin_amdgcn_mfma_f32_16x16x32_bf16(af, bf, acc[nt], 0, 0, 0);
        }
    }
    // epilogue: acc -> Ct (=Bs, free now) -> coalesced uint4 stores of Whb
    __syncthreads();                  // all waves done reading As/Bs
    unsigned short* Ct = Bs;          // stride 136 shorts (272B, 16B-aligned)
    int lrow = w * 16 + quad * 4;
#pragma unroll
    for (int r = 0; r < 4; ++r)
#pragma unroll
        for (int nt = 0; nt < 8; ++nt)
            Ct[(lrow + r) * 136 + nt * 16 + ml] = f2bf(acc[nt][r]);
    __syncthreads();
#pragma unroll
    for (int m = 0; m < 4; ++m) {
        int i = m * 256 + tid;        // 0..1023
        int r2 = i >> 4, g = i & 15;
        int rg = row0 + r2;
        uint4 v = *(const uint4*)(Ct + r2 * 136 + g * 8);
        if (rg < M)
            *(uint4*)(Whb + (size_t)rg * 128 + g * 8) = v;
    }
}

// ---------------------------------------------------------------------------
// scatter: pos = PR[dst].y + eslot[e]; write 8B record
// {src:17b | ex0:15b, ex1:15b | ex2:15b<<15}. PR[dst] is ONE random 8B gather
// for both s2 and rowptr (was two independent 4B gathers).
// ---------------------------------------------------------------------------
__global__ __launch_bounds__(256) void scatter_kernel(const int* __restrict__ ei,
                                                      const float* __restrict__ ef,
                                                      const float* __restrict__ s1,
                                                      const uint2* __restrict__ PR,
                                                      const int* __restrict__ eslot,
                                                      uint2* __restrict__ rec8, int E) {
    int e = blockIdx.x * blockDim.x + threadIdx.x;
    if (e >= E) return;
    int src = ei[e];
    int dst = ei[E + e];
    uint2 pr = PR[dst];
    float s = s1[src] + __uint_as_float(pr.x);
    s = (s >= 0.f) ? s : ALPHA * s;
    unsigned short b0 = f2bf(__expf(s * ef[e * 3 + 0]));
    unsigned short b1 = f2bf(__expf(s * ef[e * 3 + 1]));
    unsigned short b2 = f2bf(__expf(s * ef[e * 3 + 2]));
    uint2 rv;
    rv.x = (uint32)src | ((uint32)(b0 & 0x7fffu) << 17);
    rv.y = (uint32)(b1 & 0x7fffu) | ((uint32)(b2 & 0x7fffu) << 15);
    int pos = (int)pr.y + eslot[e];
    rec8[pos] = rv;
}

// ---------------------------------------------------------------------------
// agg: one wave per node, atomic-free, one pass, SCALARIZED. The whole wave
// works on one node, so rec8 records and the decoded weights are wave-uniform:
// readfirstlane them into SGPRs. Weight decode -> SALU (free pipe); gather
// address -> SGPR base + loop-invariant lane*4 (zero per-edge VALU addr math);
// FMAs use the SGPR weight directly (v_fmac v,s,v). ~13 VALU/edge vs ~22.
// x8 main loop for deeper load MLP.
// ---------------------------------------------------------------------------
__global__ __launch_bounds__(256) void agg_kernel(const uint2* __restrict__ rec8,
                                                  const int* __restrict__ rowptr,
                                                  const uint32* __restrict__ Yu,
                                                  uint32* __restrict__ zo, int N) {
    int node = (blockIdx.x * blockDim.x + threadIdx.x) >> 6;
    int lane = threadIdx.x & 63;
    if (node >= N) return;
    int beg = rowptr[node], end = rowptr[node + 1];

    float d0 = 0.f, d1 = 0.f, d2 = 0.f;
    float z0l = 0.f, z0h = 0.f, z1l = 0.f, z1h = 0.f, z2l = 0.f, z2h = 0.f;
    int j = beg;

    for (; j + 7 < end; j += 8) {
        uint2 rr[8];
#pragma unroll
        for (int q = 0; q < 8; ++q) rr[q] = rec8[j + q];
        uint32 sx[8], sy[8];
#pragma unroll
        for (int q = 0; q < 8; ++q) {
            sx[q] = __builtin_amdgcn_readfirstlane(rr[q].x);
            sy[q] = __builtin_amdgcn_readfirstlane(rr[q].y);
        }
        uint32 u[8];
#pragma unroll
        for (int q = 0; q < 8; ++q)
            u[q] = Yu[(size_t)(sx[q] & 0x1ffffu) * 64 + lane];
#pragma unroll
        for (int q = 0; q < 8; ++q) {
            float w0 = __uint_as_float((sx[q] >> 1) & 0x7fff0000u);
            float w1 = __uint_as_float((sy[q] << 16) & 0x7fff0000u);
            float w2 = __uint_as_float((sy[q] << 1) & 0x7fff0000u);
            d0 += w0; d1 += w1; d2 += w2;
            float yl = bflo(u[q]), yh = bfhi(u[q]);
            z0l += w0 * yl; z0h += w0 * yh;
            z1l += w1 * yl; z1h += w1 * yh;
            z2l += w2 * yl; z2h += w2 * yh;
        }
    }
    for (; j + 3 < end; j += 4) {
        uint2 rr[4];
#pragma unroll
        for (int q = 0; q < 4; ++q) rr[q] = rec8[j + q];
        uint32 sx[4], sy[4];
#pragma unroll
        for (int q = 0; q < 4; ++q) {
            sx[q] = __builtin_amdgcn_readfirstlane(rr[q].x);
            sy[q] = __builtin_amdgcn_readfirstlane(rr[q].y);
        }
        uint32 u[4];
#pragma unroll
        for (int q = 0; q < 4; ++q)
            u[q] = Yu[(size_t)(sx[q] & 0x1ffffu) * 64 + lane];
#pragma unroll
        for (int q = 0; q < 4; ++q) {
            float w0 = __uint_as_float((sx[q] >> 1) & 0x7fff0000u);
            float w1 = __uint_as_float((sy[q] << 16) & 0x7fff0000u);
            float w2 = __uint_as_float((sy[q] << 1) & 0x7fff0000u);
            d0 += w0; d1 += w1; d2 += w2;
            float yl = bflo(u[q]), yh = bfhi(u[q]);
            z0l += w0 * yl; z0h += w0 * yh;
            z1l += w1 * yl; z1h += w1 * yh;
            z2l += w2 * yl; z2h += w2 * yh;
        }
    }
    for (; j < end; ++j) {
        uint2 r0 = rec8[j];
        uint32 sx = __builtin_amdgcn_readfirstlane(r0.x);
        uint32 sy = __builtin_amdgcn_readfirstlane(r0.y);
        uint32 u0 = Yu[(size_t)(sx & 0x1ffffu) * 64 + lane];
        float w0 = __uint_as_float((sx >> 1) & 0x7fff0000u);
        float w1 = __uint_as_float((sy << 16) & 0x7fff0000u);
        float w2 = __uint_as_float((sy << 1) & 0x7fff0000u);
        d0 += w0; d1 += w1; d2 += w2;
        float yl = bflo(u0), yh = bfhi(u0);
        z0l += w0 * yl; z0h += w0 * yh;
        z1l += w1 * yl; z1h += w1 * yh;
        z2l += w2 * yl; z2h += w2 * yh;
    }
    float i0 = 1.f / (d0 + 1e-16f);
    float i1 = 1.f / (d1 + 1e-16f);
    float i2 = 1.f / (d2 + 1e-16f);
    size_t zb = (size_t)node * 192;
    zo[zb + lane]       = pk2bf(z0l * i0, z0h * i0);
    zo[zb + 64 + lane]  = pk2bf(z1l * i1, z1h * i1);
    zo[zb + 128 + lane] = pk2bf(z2l * i2, z2h * i2);
}

// ---------------------------------------------------------------------------
// K5: out[N,128] = z[N,384] @ Wout[384,128]. 64-row tiles, 3 k-slices of 128
// staged in LDS (same MFMA microkernel as mmy). Epilogue: fp32 acc -> LDS
// transpose (stride 132 floats) -> coalesced float4 stores.
// ---------------------------------------------------------------------------
__global__ __launch_bounds__(256) void k5_gemm(const unsigned short* __restrict__ z,
                                               const unsigned short* __restrict__ WoutT,
                                               float* __restrict__ out, int M) {
    __shared__ __align__(16) char smem[49152];
    unsigned short* As = (unsigned short*)smem;            // 64*128 bf16 = 16KB
    unsigned short* Bs = (unsigned short*)(smem + 16384);  // 128*128 bf16 = 32KB
    float* Ct = (float*)smem;                              // 64*132 f32 (epilogue)
    const int tid = threadIdx.x;
    const int lane = tid & 63, w = tid >> 6;
    const int ml = lane & 15, quad = lane >> 4;
    const int row0 = blockIdx.x * 64;

    f32x4 acc[8];
#pragma unroll
    for (int nt = 0; nt < 8; ++nt) acc[nt] = (f32x4){0.f, 0.f, 0.f, 0.f};

    for (int ks = 0; ks < 3; ++ks) {
        __syncthreads();              // prev slice compute done
#pragma unroll
        for (int m = 0; m < 4; ++m) { // stage A slice: 64 rows x 128 bf16
            int i = m * 256 + tid;
            int r = i >> 4, g = i & 15;
            int rg = row0 + r;
            uint4 v = make_uint4(0u, 0u, 0u, 0u);
            if (rg < M) v = *(const uint4*)(z + (size_t)rg * 384 + ks * 128 + g * 8);
            *(uint4*)(As + r * 128 + ((g ^ (r & 15)) * 8)) = v;
        }
#pragma unroll
        for (int m = 0; m < 8; ++m) { // stage B slice: 128 n-rows x 128 k
            int i = m * 256 + tid;
            int n = i >> 4, g = i & 15;
            uint4 v = *(const uint4*)(WoutT + n * 384 + ks * 128 + g * 8);
            *(uint4*)(Bs + n * 128 + ((g ^ (n & 15)) * 8)) = v;
        }
        __syncthreads();
#pragma unroll
        for (int kc = 0; kc < 4; ++kc) {
            int gl = ((kc * 4 + quad) ^ ml) * 8;
            short8 af = *(const short8*)(As + (w * 16 + ml) * 128 + gl);
#pragma unroll
            for (int nt = 0; nt < 8; ++nt) {
                short8 bf = *(const short8*)(Bs + (nt * 16 + ml) * 128 + gl);
                acc[nt] = __builtin_amdgcn_mfma_f32_16x16x32_bf16(af, bf, acc[nt], 0, 0, 0);
            }
        }
    }
    __syncthreads();
    int lrow = w * 16 + quad * 4;
#pragma unroll
    for (int r = 0; r < 4; ++r)
#pragma unroll
        for (int nt = 0; nt < 8; ++nt)
            Ct[(lrow + r) * 132 + nt * 16 + ml] = acc[nt][r];
    __syncthreads();
#pragma unroll
    for (int m = 0; m < 8; ++m) {
        int i = m * 256 + tid;
        int r2 = i >> 5, g = i & 31;
        int rg = row0 + r2;
        if (rg < M)
            *(float4*)(out + (size_t)rg * 128 + g * 4) = *(const float4*)(Ct + r2 * 132 + g * 4);
    }
}

// ---------------------------------------------------------------------------
extern "C" void kernel_launch(void* const* d_in, const int* in_sizes, int n_in,
                              void* d_out, int out_size, void* d_ws, size_t ws_size,
                              hipStream_t stream) {
    const float* h    = (const float*)d_in[0];
    const int*   ei   = (const int*)d_in[1];    // [2, E]
    const float* ef   = (const float*)d_in[2];  // [E, 3]
    const float* W    = (const float*)d_in[3];  // [128,128]
    const float* a1   = (const float*)d_in[4];  // [128]
    const float* a2   = (const float*)d_in[5];  // [128]
    const float* Wout = (const float*)d_in[6];  // [384,128]
    float*       out  = (float*)d_out;

    const int N = in_sizes[0] / 128;  // 50000
    const int E = in_sizes[2] / 3;    // 800000
    const int nchunk = (N + 1023) / 1024;
    const int nbh    = (E + 255) / 256;   // hist blocks
    const int nbm    = (N + 63) / 64;     // mmy blocks

    // workspace layout (rec8 first -> 16B alignment for everything vectorized)
    uint2* rec8 = (uint2*)d_ws;                           // E * 8B
    unsigned short* Whb = (unsigned short*)(rec8 + E);    // N*128 bf16 (12.8MB)
    unsigned short* WBT = Whb + (size_t)N * 128;          // 128*128 bf16
    unsigned short* WoutT = WBT + 128 * 128;              // 128*384 bf16
    float* w1f  = (float*)(WoutT + 128 * 384);            // 128
    float* w2f  = w1f + 128;                              // 128
    float* s1   = w2f + 128;                              // N
    uint2* PR   = (uint2*)(s1 + N);                       // N pairs {s2, rowptr}
    int* rowptr = (int*)(PR + N);                         // N+4 (16B-align pad)
    unsigned short* zbuf = (unsigned short*)(rowptr + N + 4);  // N*384 bf16 (38.4MB)
    // counts/eslot alias zbuf: dead before agg writes z (stream order)
    int* counts = (int*)zbuf;                             // N
    int* eslot  = counts + N;                             // E

    (void)hipMemsetAsync(counts, 0, (size_t)N * sizeof(int), stream);

    k1_hist_prep<<<nbh + 25, 256, 0, stream>>>(ei, counts, eslot, E,
                                               W, Wout, a1, a2, WBT, WoutT, w1f, w2f, nbh);
    k2_mmy_scan<<<nbm + nchunk, 256, 0, stream>>>(h, WBT, w1f, w2f, Whb, s1, PR, N,
                                                  counts, rowptr, N, E, nbm);
    scatter_kernel<<<(E + 255) / 256, 256, 0, stream>>>(ei, ef, s1, PR, eslot, rec8, E);
    agg_kernel<<<(N * 64 + 255) / 256, 256, 0, stream>>>(rec8, rowptr, (const uint32*)Whb,
                                                         (uint32*)zbuf, N);
    k5_gemm<<<(N + 63) / 64, 256, 0, stream>>>(zbuf, WoutT, out, N);
}